// Round 2
// baseline (29579.346 us; speedup 1.0000x reference)
//
#include <hip/hip_runtime.h>

typedef unsigned short u16;
typedef unsigned int   u32;
typedef unsigned long long u64;

typedef __attribute__((ext_vector_type(8))) _Float16 half8;
typedef __attribute__((ext_vector_type(4))) float    f32x4;

#define T_STEPS 512

// ---------- small helpers ----------
__device__ __forceinline__ f32x4 mfma16(uint4 a, uint4 b, f32x4 c) {
  union { uint4 u; half8 h; } A, B;
  A.u = a; B.u = b;
  return __builtin_amdgcn_mfma_f32_16x16x32_f16(A.h, B.h, c, 0, 0, 0);
}
__device__ __forceinline__ u16 f2h(float f) {
  union { _Float16 h; u16 u; } x; x.h = (_Float16)f; return x.u;
}
__device__ __forceinline__ float h2f(u16 v) {
  union { _Float16 h; u16 u; } x; x.u = v; return (float)x.h;
}
// agent-scope (device-coherent) accesses for cross-workgroup data
__device__ __forceinline__ float ldf(const float* p) {
  return __hip_atomic_load(p, __ATOMIC_RELAXED, __HIP_MEMORY_SCOPE_AGENT);
}
__device__ __forceinline__ void stf(float* p, float v) {
  __hip_atomic_store(p, v, __ATOMIC_RELAXED, __HIP_MEMORY_SCOPE_AGENT);
}
__device__ __forceinline__ void sth(u16* p, u16 v) {
  __hip_atomic_store(p, v, __ATOMIC_RELAXED, __HIP_MEMORY_SCOPE_AGENT);
}
__device__ __forceinline__ u64 ld8(const u64* p) {
  return __hip_atomic_load(p, __ATOMIC_RELAXED, __HIP_MEMORY_SCOPE_AGENT);
}
__device__ __forceinline__ float sigm(float x)  { return 1.0f / (1.0f + __expf(-x)); }
__device__ __forceinline__ float tanhx(float x) { return 2.0f / (1.0f + __expf(-2.0f * x)) - 1.0f; }
__device__ __forceinline__ float actf(int a, float x) {
  if (a == 0) return tanhx(x);
  if (a == 1) return fmaxf(x, 0.0f);
  if (a == 2) return sigm(x);
  return x;
}

// stage a [32][512] fp16 state (group rows rb..rb+32) from global into LDS in exact
// MFMA A-fragment order: dst[(mt*16+kc)*64+lane] = S[rb+mt*16+(lane&15)][kc*32+(lane>>4)*8 .. +8]
__device__ __forceinline__ void stage32(uint4* dst, const u16* src, int rb, int tid) {
#pragma unroll
  for (int it = 0; it < 8; ++it) {
    int d = tid + it * 256;                 // 0..2047
    int lane = d & 63, kcL = (d >> 6) & 15, mtL = d >> 10;
    int lm = mtL * 16 + (lane & 15);
    int k8 = kcL * 4 + (lane >> 4);
    const u64* p = (const u64*)(src + (size_t)(rb + lm) * 512 + (size_t)k8 * 8);
    u64 lo = ld8(p), hi = ld8(p + 1);
    uint4 v; v.x = (u32)lo; v.y = (u32)(lo >> 32); v.z = (u32)hi; v.w = (u32)(hi >> 32);
    dst[d] = v;
  }
}

// distributed-flag barrier over the 64 workgroups of one batch-group.
// flag[i] written only by wg i (monotonic epoch, no reset/ABA). __syncthreads drains
// vmcnt of all waves before the release store; wave-0 lanes poll all 64 flags in parallel.
__device__ __forceinline__ void gbar(u32* flg, int wgi, u32 epoch) {
  __syncthreads();
  if (threadIdx.x < 64) {
    if (threadIdx.x == 0)
      __hip_atomic_store(flg + (size_t)wgi * 4, epoch, __ATOMIC_RELEASE, __HIP_MEMORY_SCOPE_AGENT);
    u32* p = flg + (size_t)threadIdx.x * 4;
    while (__hip_atomic_load(p, __ATOMIC_RELAXED, __HIP_MEMORY_SCOPE_AGENT) < epoch) {}
  }
  __builtin_amdgcn_fence(__ATOMIC_ACQUIRE, "agent");
  __syncthreads();
}

// epilogue: 16x16 preact tile (cols 0-7 = gate, 8-15 = candidate for same j):
// s_new = s_prev + sigmoid(gate)*(act(cand) - s_prev)
__device__ __forceinline__ void epi(f32x4 acc, int act, int lane, int mt, int rb, int jb,
                                    const float* spf, float* sof, u16* soh, float* msum) {
  int n = lane & 15, r0 = (lane >> 4) * 4;
  float part[4];
#pragma unroll
  for (int i = 0; i < 4; ++i) part[i] = __shfl_xor(acc[i], 8);
  if (n < 8) {
    int j = jb * 8 + n;
#pragma unroll
    for (int i = 0; i < 4; ++i) {
      int m = rb + mt * 16 + r0 + i;
      float c = sigm(acc[i]);
      float h = actf(act, part[i]);
      float sp = ldf(spf + m * 512 + j);
      float sn = sp + c * (h - sp);
      if (sof) stf(sof + m * 512 + j, sn);
      if (soh) sth(soh + m * 512 + j, f2h(sn));
      atomicAdd(msum + m * 512 + j, sn);
    }
  }
}

// ---------- prelude 1: pack weights (f32 -> fp16) into MFMA B-fragment lane order ----------
// pack w: 0 = W0[:512,:] (x part), 1 = W0[512:,:] (h part), 2+i = Ws[i]
__global__ __launch_bounds__(256) void pack_kernel(const float* __restrict__ w0,
                                                   const float* __restrict__ wsrc,
                                                   u16* __restrict__ wp) {
  int gid = blockIdx.x * 256 + threadIdx.x;  // < 655360
  int w = gid >> 16, c = gid & 65535;
  int jb = c >> 10, kc = (c >> 6) & 15, lane = c & 63;
  int nl = lane & 15, kh = lane >> 4;
  int n = (nl < 8) ? (jb * 8 + nl) : (512 + jb * 8 + nl - 8);
  int k = kc * 32 + kh * 8;
  const float* s;
  if (w == 0)      s = w0 + (size_t)k * 1024 + n;
  else if (w == 1) s = w0 + (size_t)(512 + k) * 1024 + n;
  else             s = wsrc + (size_t)(w - 2) * 524288 + (size_t)k * 1024 + n;
  u32 e[8];
#pragma unroll
  for (int i = 0; i < 8; ++i) e[i] = (u32)f2h(s[(size_t)i * 1024]);
  uint4 v;
  v.x = e[0] | (e[1] << 16); v.y = e[2] | (e[3] << 16);
  v.z = e[4] | (e[5] << 16); v.w = e[6] | (e[7] << 16);
  ((uint4*)wp)[gid] = v;
}

// ---------- prelude 2: XW[t][m][n] = x[t] @ W0[:512,:]  (fp16 out) ----------
__global__ __launch_bounds__(256) void xw_kernel(const float* __restrict__ x,
                                                 const u16* __restrict__ wp,
                                                 u16* __restrict__ xw) {
  __shared__ uint4 smem[4096];  // 64KB: full x[t] in A-frag layout [mt4][kc16][lane]
  int t = blockIdx.x >> 4, jbg = blockIdx.x & 15;
  int tid = threadIdx.x, lane = tid & 63, wv = tid >> 6;
  const float* src = x + (size_t)t * 64 * 512;
#pragma unroll
  for (int it = 0; it < 16; ++it) {
    int d = tid + it * 256;
    int ln = d & 63, kcL = (d >> 6) & 15, mtL = d >> 10;
    int lm = mtL * 16 + (ln & 15);
    int k8 = kcL * 4 + (ln >> 4);
    const float* p = src + (size_t)lm * 512 + (size_t)k8 * 8;
    float4 a = *(const float4*)p;
    float4 b = *(const float4*)(p + 4);
    uint4 v;
    v.x = (u32)f2h(a.x) | ((u32)f2h(a.y) << 16);
    v.y = (u32)f2h(a.z) | ((u32)f2h(a.w) << 16);
    v.z = (u32)f2h(b.x) | ((u32)f2h(b.y) << 16);
    v.w = (u32)f2h(b.z) | ((u32)f2h(b.w) << 16);
    smem[d] = v;
  }
  __syncthreads();
  int jb = jbg * 4 + wv;
  const uint4* bp = (const uint4*)wp + (size_t)jb * 16 * 64;  // pack 0 = W0x
  f32x4 acc[4] = {{0,0,0,0},{0,0,0,0},{0,0,0,0},{0,0,0,0}};
#pragma unroll
  for (int kc = 0; kc < 16; ++kc) {
    uint4 b = bp[kc * 64 + lane];
#pragma unroll
    for (int m4 = 0; m4 < 4; ++m4)
      acc[m4] = mfma16(smem[(m4 * 16 + kc) * 64 + lane], b, acc[m4]);
  }
  int n = lane & 15, r0 = (lane >> 4) * 4;
  int colg = (n < 8) ? (jb * 8 + n) : (512 + jb * 8 + n - 8);
#pragma unroll
  for (int m4 = 0; m4 < 4; ++m4)
#pragma unroll
    for (int i = 0; i < 4; ++i) {
      int m = m4 * 16 + r0 + i;
      xw[((size_t)t * 64 + m) * 1024 + colg] = f2h(acc[m4][i]);
    }
}

// ---------- prelude 3: fp16 mirror of h_in ----------
__global__ __launch_bounds__(256) void init_hh(const float* __restrict__ h, u16* __restrict__ hh) {
  int i = blockIdx.x * 256 + threadIdx.x;
  if (i < 32768) hh[i] = f2h(h[i]);
}

// ---------- the persistent recurrence kernel ----------
// 128 wgs: jb = wg&63 (j-block, 8 state cols), g = wg>>6 (batch rows g*32..+32).
// stride-64 pairing keeps the two wgs sharing a jb weight slice on the same XCD.
// waves: mt = wid&1 (16-row half), sel = wid>>1 (role).
__global__ __launch_bounds__(256) void recur_kernel(
    const u16* __restrict__ xw, const float* __restrict__ h_in,
    const u16* __restrict__ wp,
    float* __restrict__ sf, u16* __restrict__ sh,
    float* __restrict__ hf, u16* __restrict__ hh,
    float* __restrict__ msum, u32* __restrict__ bar,
    float* __restrict__ out) {
  __shared__ uint4 smem[4096];  // 2 x 32KB state slots (scratch aliased after syncs)
  const int wg = blockIdx.x;
  const int jb = wg & 63, g = wg >> 6;
  const int rb = g * 32;
  const int tid = threadIdx.x;
  const int lane = tid & 63;
  const int wid = tid >> 6;
  const int mt = wid & 1, sel = wid >> 1;
  const int n = lane & 15, r0 = (lane >> 4) * 4;
  u32* flg = bar + (size_t)g * 256;
  u32 ep = 0;
  const uint4* wp4 = (const uint4*)wp;

  for (int t = 0; t < T_STEPS; ++t) {
    // ---------- stage A: ch0 = XW[t] + h @ W0h ; s0 ----------
    {
      const u16* hsrc = (t == 0) ? hh : hh;  // hh pre-initialized from h_in by init_hh
      stage32(smem, hsrc, rb, tid);
      __syncthreads();
      f32x4 acc = {0.f, 0.f, 0.f, 0.f};
      const uint4* bp = wp4 + (size_t)1 * 65536 + (size_t)jb * 16 * 64;
#pragma unroll
      for (int kc = 0; kc < 8; ++kc) {
        int kk = sel * 8 + kc;  // K split across sel
        acc = mfma16(smem[(mt * 16 + kk) * 64 + lane], bp[kk * 64 + lane], acc);
      }
      __syncthreads();
      float* scr = (float*)smem;  // 2KB partial-sum scratch (aliases slot0, safe after sync)
      if (sel == 1) {
#pragma unroll
        for (int i = 0; i < 4; ++i) scr[(mt * 64 + lane) * 4 + i] = acc[i];
      }
      __syncthreads();
      if (sel == 0) {
        float v[4];
#pragma unroll
        for (int i = 0; i < 4; ++i) {
          int m = rb + mt * 16 + r0 + i;
          int colg = (n < 8) ? (jb * 8 + n) : (512 + jb * 8 + n - 8);
          v[i] = acc[i] + scr[(mt * 64 + lane) * 4 + i] +
                 h2f(xw[((size_t)t * 64 + m) * 1024 + colg]);
        }
        float part[4];
#pragma unroll
        for (int i = 0; i < 4; ++i) part[i] = __shfl_xor(v[i], 8);
        if (n < 8) {
          int j = jb * 8 + n;
#pragma unroll
          for (int i = 0; i < 4; ++i) {
            int m = rb + mt * 16 + r0 + i;
            float c0 = sigm(v[i]);
            float h0 = tanhx(part[i]);
            float sp = (t == 0) ? h_in[m * 512 + j] : ldf(hf + m * 512 + j);
            float s0 = sp + c0 * (h0 - sp);
            stf(sf + m * 512 + j, s0);
            sth(sh + m * 512 + j, f2h(s0));
          }
        }
      }
    }
    gbar(flg, jb, ++ep);
    // ---------- stage B: steps 0 (tanh -> s1), 1 (relu -> s2), pred s0 ----------
    {
      stage32(smem, sh, rb, tid);  // s0
      __syncthreads();
      f32x4 acc = {0.f, 0.f, 0.f, 0.f};
      const uint4* bp = wp4 + (size_t)(2 + sel) * 65536 + (size_t)jb * 16 * 64;
#pragma unroll
      for (int kc = 0; kc < 16; ++kc)
        acc = mfma16(smem[(mt * 16 + kc) * 64 + lane], bp[kc * 64 + lane], acc);
      epi(acc, sel == 0 ? 0 : 1, lane, mt, rb, jb,
          sf, sf + (1 + sel) * 32768, sh + (1 + sel) * 32768, msum);
    }
    gbar(flg, jb, ++ep);
    // ---------- stage C: steps 2,3 (pred s1 -> s3,s4), steps 4,5 (pred s2 -> s5,s6) ----------
    {
      stage32(smem,        sh + 1 * 32768, rb, tid);  // s1 -> slot0
      stage32(smem + 2048, sh + 2 * 32768, rb, tid);  // s2 -> slot1
      __syncthreads();
      const uint4* As = smem + sel * 2048;
      f32x4 acc0 = {0,0,0,0}, acc1 = {0,0,0,0};
      const uint4* bp0 = wp4 + (size_t)(4 + 2 * sel) * 65536 + (size_t)jb * 16 * 64;
      const uint4* bp1 = bp0 + 65536;
#pragma unroll
      for (int kc = 0; kc < 16; ++kc) {
        uint4 a = As[(mt * 16 + kc) * 64 + lane];
        acc0 = mfma16(a, bp0[kc * 64 + lane], acc0);
        acc1 = mfma16(a, bp1[kc * 64 + lane], acc1);
      }
      if (sel == 0) {
        epi(acc0, 2, lane, mt, rb, jb, sf + 1 * 32768, sf + 3 * 32768, sh + 3 * 32768, msum);
        epi(acc1, 3, lane, mt, rb, jb, sf + 1 * 32768, sf + 4 * 32768, sh + 4 * 32768, msum);
      } else {
        epi(acc0, 0, lane, mt, rb, jb, sf + 2 * 32768, nullptr, nullptr, msum);  // s5: mean only
        epi(acc1, 1, lane, mt, rb, jb, sf + 2 * 32768, nullptr, nullptr, msum);  // s6: mean only
      }
    }
    gbar(flg, jb, ++ep);
    // ---------- stage D: step 6 (pred s3, sigmoid), step 7 (pred s4, id), mean -> h ----------
    {
      stage32(smem,        sh + 3 * 32768, rb, tid);  // s3
      stage32(smem + 2048, sh + 4 * 32768, rb, tid);  // s4
      __syncthreads();
      const uint4* As = smem + sel * 2048;
      f32x4 acc = {0,0,0,0};
      const uint4* bp = wp4 + (size_t)(8 + sel) * 65536 + (size_t)jb * 16 * 64;
#pragma unroll
      for (int kc = 0; kc < 16; ++kc)
        acc = mfma16(As[(mt * 16 + kc) * 64 + lane], bp[kc * 64 + lane], acc);
      __syncthreads();                 // all waves done reading frags; scratch may alias slot0
      float* scr = (float*)smem;
      float part[4];
#pragma unroll
      for (int i = 0; i < 4; ++i) part[i] = __shfl_xor(acc[i], 8);
      if (sel == 1 && n < 8) {        // step 7: s8 = s4 + sig(c)*(hh_cand - s4), act=id
        int j = jb * 8 + n;
#pragma unroll
        for (int i = 0; i < 4; ++i) {
          int m = rb + mt * 16 + r0 + i;
          float c = sigm(acc[i]);
          float sp = ldf(sf + 4 * 32768 + m * 512 + j);
          scr[(mt * 8 + n) * 16 + r0 + i] = sp + c * (part[i] - sp);
        }
      }
      __syncthreads();
      if (sel == 0 && n < 8) {        // step 6 + finalize h = (msum + s7 + s8)/8
        int j = jb * 8 + n;
#pragma unroll
        for (int i = 0; i < 4; ++i) {
          int m = rb + mt * 16 + r0 + i;
          float c = sigm(acc[i]);
          float hcand = sigm(part[i]);
          float sp = ldf(sf + 3 * 32768 + m * 512 + j);
          float s7 = sp + c * (hcand - sp);
          float s8 = scr[(mt * 8 + n) * 16 + r0 + i];
          float ms = ldf(msum + m * 512 + j);
          float hn = (ms + s7 + s8) * 0.125f;
          stf(hf + m * 512 + j, hn);
          sth(hh + m * 512 + j, f2h(hn));
          out[((size_t)t * 64 + m) * 512 + j] = hn;
          stf(msum + m * 512 + j, 0.0f);  // ready for next timestep
          if (t == 511) out[(size_t)512 * 64 * 512 + m * 512 + j] = hn;
        }
      }
    }
    gbar(flg, jb, ++ep);
  }
}

extern "C" void kernel_launch(void* const* d_in, const int* in_sizes, int n_in,
                              void* d_out, int out_size, void* d_ws, size_t ws_size,
                              hipStream_t stream) {
  const float* x_in = (const float*)d_in[0];  // [512,64,512] f32
  const float* h_in = (const float*)d_in[1];  // [1,64,512]  f32
  const float* w0   = (const float*)d_in[2];  // [1024,1024] f32
  const float* wsrc = (const float*)d_in[3];  // [8,512,1024] f32
  float* out = (float*)d_out;
  char* ws = (char*)d_ws;

  const size_t O_BAR  = 0;                       // 2048 B (2 groups x 64 flags x 16B stride)
  const size_t O_MSUM = 2048;                    // 131072 B ([64][512] f32)
  const size_t O_WP   = O_MSUM + 131072;         // 10 MB packed fp16 weights
  const size_t O_XW   = O_WP + 10485760;         // 64 MB XW fp16 [512][64][1024]
  const size_t O_SF   = O_XW + 67108864;         // s0..s4 f32: 5*131072
  const size_t O_HF   = O_SF + 655360;           // h f32
  const size_t O_SH   = O_HF + 131072;           // s0..s4 fp16: 5*65536
  const size_t O_HH   = O_SH + 327680;           // h fp16
  const size_t NEED   = O_HH + 65536;            // ~75.3 MB
  if (ws_size < NEED) return;  // insufficient scratch -> visible absmax failure

  u32*   bar  = (u32*)(ws + O_BAR);
  float* msum = (float*)(ws + O_MSUM);
  u16*   wp   = (u16*)(ws + O_WP);
  u16*   xw   = (u16*)(ws + O_XW);
  float* sf   = (float*)(ws + O_SF);
  float* hf   = (float*)(ws + O_HF);
  u16*   sh   = (u16*)(ws + O_SH);
  u16*   hh   = (u16*)(ws + O_HH);

  hipMemsetAsync(ws, 0, O_WP, stream);  // zero barrier flags + msum every call
  pack_kernel<<<dim3(2560), dim3(256), 0, stream>>>(w0, wsrc, wp);
  xw_kernel<<<dim3(8192), dim3(256), 0, stream>>>(x_in, wp, xw);
  init_hh<<<dim3(128), dim3(256), 0, stream>>>(h_in, hh);
  recur_kernel<<<dim3(128), dim3(256), 0, stream>>>(xw, h_in, wp, sf, sh, hf, hh, msum, bar, out);
}

// Round 3
// 18868.332 us; speedup vs baseline: 1.5677x; 1.5677x over previous
//
#include <hip/hip_runtime.h>

typedef unsigned short u16;
typedef unsigned int   u32;
typedef unsigned long long u64;

typedef __attribute__((ext_vector_type(8))) _Float16 half8;
typedef __attribute__((ext_vector_type(4))) float    f32x4;

#define T_STEPS 512

// ---------- helpers ----------
__device__ __forceinline__ f32x4 mfma16(uint4 a, uint4 b, f32x4 c) {
  union { uint4 u; half8 h; } A, B;
  A.u = a; B.u = b;
  return __builtin_amdgcn_mfma_f32_16x16x32_f16(A.h, B.h, c, 0, 0, 0);
}
__device__ __forceinline__ u16 f2h(float f) {
  union { _Float16 h; u16 u; } x; x.h = (_Float16)f; return x.u;
}
__device__ __forceinline__ float h2f(u16 v) {
  union { _Float16 h; u16 u; } x; x.u = v; return (float)x.h;
}
// agent-scope (device-coherent, bypass L1/L2) for cross-workgroup state
__device__ __forceinline__ void sth(u16* p, u16 v) {
  __hip_atomic_store(p, v, __ATOMIC_RELAXED, __HIP_MEMORY_SCOPE_AGENT);
}
__device__ __forceinline__ u64 ld8(const u64* p) {
  return __hip_atomic_load(p, __ATOMIC_RELAXED, __HIP_MEMORY_SCOPE_AGENT);
}
__device__ __forceinline__ float sigm(float x)  { return 1.0f / (1.0f + __expf(-x)); }
__device__ __forceinline__ float tanhx(float x) { return 2.0f / (1.0f + __expf(-2.0f * x)) - 1.0f; }

// load the wave's 16-row A-fragment set (16 uint4) straight from global
// af[kc] = S[rb+mt*16+(lane&15)][kc*32+(lane>>4)*8 .. +8]  (rowoff precomputed)
__device__ __forceinline__ void frag_load(uint4* af, const u16* buf, int rowoff) {
#pragma unroll
  for (int kc = 0; kc < 16; ++kc) {
    const u64* p = (const u64*)(buf + rowoff + kc * 32);
    u64 lo = ld8(p), hi = ld8(p + 1);
    af[kc].x = (u32)lo; af[kc].y = (u32)(lo >> 32);
    af[kc].z = (u32)hi; af[kc].w = (u32)(hi >> 32);
  }
}
// 16-MFMA matmul: A-frags (regs) x LDS weight slice
__device__ __forceinline__ f32x4 mm(const uint4* af, const uint4* lw, int slice, int lane) {
  f32x4 acc = {0.f, 0.f, 0.f, 0.f};
#pragma unroll
  for (int kc = 0; kc < 16; ++kc)
    acc = mfma16(af[kc], lw[slice * 1024 + kc * 64 + lane], acc);
  return acc;
}

// distributed-flag barrier over 64 wgs of one group; flags 64B apart (no line sharing).
// __syncthreads drains every wave's vmem (stores at LLC) before the release store.
__device__ __forceinline__ void gbar(u32* flg, int wgi, u32 epoch) {
  __syncthreads();
  if (threadIdx.x < 64) {
    if (threadIdx.x == 0)
      __hip_atomic_store(flg + (size_t)wgi * 16, epoch, __ATOMIC_RELEASE, __HIP_MEMORY_SCOPE_AGENT);
    u32* p = flg + (size_t)threadIdx.x * 16;
    while (__hip_atomic_load(p, __ATOMIC_RELAXED, __HIP_MEMORY_SCOPE_AGENT) < epoch) {}
  }
  __builtin_amdgcn_fence(__ATOMIC_ACQUIRE, "agent");
  __syncthreads();
}

// ---------- prelude 1: pack weights (f32 -> fp16) into MFMA B-fragment lane order ----------
// pack w: 0 = W0[:512,:] (x part), 1 = W0[512:,:] (h part), 2+i = Ws[i]
__global__ __launch_bounds__(256) void pack_kernel(const float* __restrict__ w0,
                                                   const float* __restrict__ wsrc,
                                                   u16* __restrict__ wp) {
  int gid = blockIdx.x * 256 + threadIdx.x;  // < 655360
  int w = gid >> 16, c = gid & 65535;
  int jb = c >> 10, kc = (c >> 6) & 15, lane = c & 63;
  int nl = lane & 15, kh = lane >> 4;
  int n = (nl < 8) ? (jb * 8 + nl) : (512 + jb * 8 + nl - 8);
  int k = kc * 32 + kh * 8;
  const float* s;
  if (w == 0)      s = w0 + (size_t)k * 1024 + n;
  else if (w == 1) s = w0 + (size_t)(512 + k) * 1024 + n;
  else             s = wsrc + (size_t)(w - 2) * 524288 + (size_t)k * 1024 + n;
  u32 e[8];
#pragma unroll
  for (int i = 0; i < 8; ++i) e[i] = (u32)f2h(s[(size_t)i * 1024]);
  uint4 v;
  v.x = e[0] | (e[1] << 16); v.y = e[2] | (e[3] << 16);
  v.z = e[4] | (e[5] << 16); v.w = e[6] | (e[7] << 16);
  ((uint4*)wp)[gid] = v;
}

// ---------- prelude 2: XW = x[t] @ W0x, stored PACKED in C-frag layout ----------
// xwp[((t*64 + jb)*4 + m4)*64 + lane] = u64 of 4 fp16 = preact rows m4*16+r0+0..3, col colg(lane)
__global__ __launch_bounds__(256) void xw_kernel(const float* __restrict__ x,
                                                 const u16* __restrict__ wp,
                                                 u64* __restrict__ xwp) {
  __shared__ uint4 smem[4096];  // 64KB: full x[t] in A-frag layout
  int t = blockIdx.x >> 4, jbg = blockIdx.x & 15;
  int tid = threadIdx.x, lane = tid & 63, wv = tid >> 6;
  const float* src = x + (size_t)t * 64 * 512;
#pragma unroll
  for (int it = 0; it < 16; ++it) {
    int d = tid + it * 256;
    int ln = d & 63, kcL = (d >> 6) & 15, mtL = d >> 10;
    int lm = mtL * 16 + (ln & 15);
    int k8 = kcL * 4 + (ln >> 4);
    const float* p = src + (size_t)lm * 512 + (size_t)k8 * 8;
    float4 a = *(const float4*)p;
    float4 b = *(const float4*)(p + 4);
    uint4 v;
    v.x = (u32)f2h(a.x) | ((u32)f2h(a.y) << 16);
    v.y = (u32)f2h(a.z) | ((u32)f2h(a.w) << 16);
    v.z = (u32)f2h(b.x) | ((u32)f2h(b.y) << 16);
    v.w = (u32)f2h(b.z) | ((u32)f2h(b.w) << 16);
    smem[d] = v;
  }
  __syncthreads();
  int jb = jbg * 4 + wv;
  const uint4* bp = (const uint4*)wp + (size_t)jb * 1024;  // pack 0 = W0x
  f32x4 acc[4] = {{0,0,0,0},{0,0,0,0},{0,0,0,0},{0,0,0,0}};
#pragma unroll
  for (int kc = 0; kc < 16; ++kc) {
    uint4 b = bp[kc * 64 + lane];
#pragma unroll
    for (int m4 = 0; m4 < 4; ++m4)
      acc[m4] = mfma16(smem[(m4 * 16 + kc) * 64 + lane], b, acc[m4]);
  }
#pragma unroll
  for (int m4 = 0; m4 < 4; ++m4) {
    u32 lo = (u32)f2h(acc[m4][0]) | ((u32)f2h(acc[m4][1]) << 16);
    u32 hi = (u32)f2h(acc[m4][2]) | ((u32)f2h(acc[m4][3]) << 16);
    xwp[((size_t)(t * 64 + jb) * 4 + m4) * 64 + lane] = (u64)lo | ((u64)hi << 32);
  }
}

// ---------- prelude 3: fp16 mirror of h_in ----------
__global__ __launch_bounds__(256) void init_hh(const float* __restrict__ h, u16* __restrict__ hh) {
  int i = blockIdx.x * 256 + threadIdx.x;
  if (i < 32768) hh[i] = f2h(h[i]);
}

// ---------- persistent recurrence ----------
// 128 wgs: jb = wg&63, g = wg>>6 (rows g*32..+32). 4 waves: mt = wid&1 (16-row tile),
// sel = wid>>1 (role). All 9 weight jb-slices LDS-resident (144KB). fp32 state chain
// in registers; cross-wave handoff via 3KB LDS scratch. Global traffic per stage:
// A-frag reads of the one predecessor state + 4x2B fp16 state writes. 4 barriers/step.
__global__ __launch_bounds__(256) void recur_kernel(
    const u64* __restrict__ xwp, const float* __restrict__ h_in,
    const u16* __restrict__ wp,
    u16* __restrict__ sh,   // s0..s4 fp16 [5][64][512]
    u16* __restrict__ hh,   // h fp16 [64][512]
    u32* __restrict__ bar,
    float* __restrict__ out) {
  extern __shared__ char smem_raw[];
  uint4* lw   = (uint4*)smem_raw;                 // [9][16][64] uint4 = 147456B
  float* scr  = (float*)(smem_raw + 147456);      // 768 f32
  float* scr_s0 = scr;                            // [32][8]
  float* scr_s4 = scr + 256;
  float* scr_m1 = scr + 512;

  const int wg = blockIdx.x;
  const int jb = wg & 63, g = wg >> 6;
  const int rb = g * 32;
  const int tid = threadIdx.x;
  const int lane = tid & 63;
  const int wid = tid >> 6;
  const int mt = wid & 1, sel = wid >> 1;
  const int n = lane & 15, r0 = (lane >> 4) * 4;
  const int rowoff = (rb + mt * 16 + n) * 512 + (lane >> 4) * 8;  // fp16 elems
  const int jj = jb * 8 + n;                   // owner column (valid n<8)
  const int sbase = (mt * 16 + r0) * 8 + n;    // scr index, +i*8
  u32* flg = bar + (size_t)g * 1024;
  const uint4* wp4 = (const uint4*)wp;

  // preload all 9 weight jb-slices into LDS (slice s = pack 1+s)
  for (int idx = tid; idx < 9216; idx += 256) {
    int s = idx >> 10, rem = idx & 1023;
    lw[idx] = wp4[(size_t)(1 + s) * 65536 + (size_t)jb * 1024 + rem];
  }
  __syncthreads();

  float h_reg[4];                // fp32 h for this lane's (rows, jj)
  float mean[4] = {0, 0, 0, 0};  // sel0: s1+s3+s4+s7 ; sel1: s2+s5+s6+s8
  float s0r[4], s1r[4], s3r[4];  // register fp32 chain (sel-dependent meaning)
  u32 ep = 0;
  u64 sink = 0;

  for (int t = 0; t < T_STEPS; ++t) {
    // ---------- stage A: ch0 = XW[t] + h @ W0h -> s0 (sel0 waves only) ----------
    if (sel == 0) {
      uint4 af[16];
      frag_load(af, hh, rowoff);
      u64 xv = xwp[((size_t)(t * 64 + jb) * 4 + (g * 2 + mt)) * 64 + lane];
      f32x4 acc = mm(af, lw, 0, lane);
      float v[4], part[4];
#pragma unroll
      for (int i = 0; i < 4; ++i) v[i] = acc[i] + h2f((u16)(xv >> (16 * i)));
#pragma unroll
      for (int i = 0; i < 4; ++i) part[i] = __shfl_xor(v[i], 8);
      if (n < 8) {
#pragma unroll
        for (int i = 0; i < 4; ++i) {
          int m = rb + mt * 16 + r0 + i;
          float hp = (t == 0) ? h_in[m * 512 + jj] : h_reg[i];
          float s0 = hp + sigm(v[i]) * (tanhx(part[i]) - hp);
          s0r[i] = s0;
          scr_s0[sbase + i * 8] = s0;
          sth(sh + 0 * 32768 + m * 512 + jj, f2h(s0));
        }
      }
    }
    gbar(flg, jb, ++ep);
    // ---------- stage B: s1 = tanh-step(s0) [sel0], s2 = relu-step(s0) [sel1] ----------
    {
      uint4 af[16];
      frag_load(af, sh + 0 * 32768, rowoff);
      f32x4 acc = mm(af, lw, 1 + sel, lane);
      float part[4];
#pragma unroll
      for (int i = 0; i < 4; ++i) part[i] = __shfl_xor(acc[i], 8);
      if (n < 8) {
#pragma unroll
        for (int i = 0; i < 4; ++i) {
          int m = rb + mt * 16 + r0 + i;
          float sp = (sel == 0) ? s0r[i] : scr_s0[sbase + i * 8];
          float hc = (sel == 0) ? tanhx(part[i]) : fmaxf(part[i], 0.f);
          float sn = sp + sigm(acc[i]) * (hc - sp);
          s1r[i] = sn;      // sel0: s1 ; sel1: s2
          mean[i] = sn;     // first mean term (implicit reset each step)
          sth(sh + (size_t)(1 + sel) * 32768 + m * 512 + jj, f2h(sn));
        }
      }
    }
    gbar(flg, jb, ++ep);
    // ---------- stage C: sel0: s3,s4 from s1 ; sel1: s5,s6 from s2 (mean-only) ----------
    {
      uint4 af[16];
      frag_load(af, sh + (size_t)(1 + sel) * 32768, rowoff);
      f32x4 a0 = {0, 0, 0, 0}, a1 = {0, 0, 0, 0};
#pragma unroll
      for (int kc = 0; kc < 16; ++kc) {
        uint4 a = af[kc];
        a0 = mfma16(a, lw[(3 + 2 * sel) * 1024 + kc * 64 + lane], a0);
        a1 = mfma16(a, lw[(4 + 2 * sel) * 1024 + kc * 64 + lane], a1);
      }
      float p0[4], p1[4];
#pragma unroll
      for (int i = 0; i < 4; ++i) { p0[i] = __shfl_xor(a0[i], 8); p1[i] = __shfl_xor(a1[i], 8); }
      if (n < 8) {
#pragma unroll
        for (int i = 0; i < 4; ++i) {
          int m = rb + mt * 16 + r0 + i;
          float sp = s1r[i];
          if (sel == 0) {
            float s3 = sp + sigm(a0[i]) * (sigm(p0[i]) - sp);        // step2: sigmoid
            float s4 = sp + sigm(a1[i]) * (p1[i] - sp);              // step3: identity
            mean[i] += s3 + s4;
            s3r[i] = s3;
            scr_s4[sbase + i * 8] = s4;
            sth(sh + (size_t)3 * 32768 + m * 512 + jj, f2h(s3));
            sth(sh + (size_t)4 * 32768 + m * 512 + jj, f2h(s4));
          } else {
            float s5 = sp + sigm(a0[i]) * (tanhx(p0[i]) - sp);       // step4: tanh
            float s6 = sp + sigm(a1[i]) * (fmaxf(p1[i], 0.f) - sp);  // step5: relu
            mean[i] += s5 + s6;
          }
        }
      }
    }
    gbar(flg, jb, ++ep);
    // ---------- stage D: sel0: s7 from s3 ; sel1: s8 from s4 ; h = mean/8 ----------
    {
      uint4 af[16];
      frag_load(af, sh + (size_t)(3 + sel) * 32768, rowoff);
      if (sel == 0) {  // prefetch next step's XW into L2/L1 (normal cached load)
        int tn = (t < T_STEPS - 1) ? t + 1 : t;
        sink += xwp[((size_t)(tn * 64 + jb) * 4 + (g * 2 + mt)) * 64 + lane];
      }
      f32x4 acc = mm(af, lw, 7 + sel, lane);
      float part[4];
#pragma unroll
      for (int i = 0; i < 4; ++i) part[i] = __shfl_xor(acc[i], 8);
      if (sel == 1 && n < 8) {
#pragma unroll
        for (int i = 0; i < 4; ++i) {
          float sp = scr_s4[sbase + i * 8];
          float s8 = sp + sigm(acc[i]) * (part[i] - sp);             // step7: identity
          mean[i] += s8;
          scr_m1[sbase + i * 8] = mean[i];
        }
      }
      __syncthreads();
      if (sel == 0 && n < 8) {
#pragma unroll
        for (int i = 0; i < 4; ++i) {
          int m = rb + mt * 16 + r0 + i;
          float sp = s3r[i];
          float s7 = sp + sigm(acc[i]) * (sigm(part[i]) - sp);       // step6: sigmoid
          float hn = (mean[i] + s7 + scr_m1[sbase + i * 8]) * 0.125f;
          h_reg[i] = hn;
          sth(hh + m * 512 + jj, f2h(hn));
          out[((size_t)t * 64 + m) * 512 + jj] = hn;
          if (t == T_STEPS - 1) out[(size_t)T_STEPS * 64 * 512 + m * 512 + jj] = hn;
        }
      }
    }
    gbar(flg, jb, ++ep);
  }
  if (sink == 0xFFFFFFFFFFFFFFFFull) out[0] = 0.f;  // keep prefetch alive
}

extern "C" void kernel_launch(void* const* d_in, const int* in_sizes, int n_in,
                              void* d_out, int out_size, void* d_ws, size_t ws_size,
                              hipStream_t stream) {
  const float* x_in = (const float*)d_in[0];  // [512,64,512] f32
  const float* h_in = (const float*)d_in[1];  // [1,64,512]  f32
  const float* w0   = (const float*)d_in[2];  // [1024,1024] f32
  const float* wsrc = (const float*)d_in[3];  // [8,512,1024] f32
  float* out = (float*)d_out;
  char* ws = (char*)d_ws;

  const size_t O_BAR = 0;                       // 8 KB (2 groups x 64 flags x 64B)
  const size_t O_WP  = 8192;                    // 10 MB packed fp16 weights
  const size_t O_XWP = O_WP + 10485760;         // 64 MB packed XW (u64 frags)
  const size_t O_SH  = O_XWP + 67108864;        // s0..s4 fp16: 5 x 65536 B
  const size_t O_HH  = O_SH + 327680;           // h fp16
  const size_t NEED  = O_HH + 65536;            // ~74.4 MB
  if (ws_size < NEED) return;

  u32* bar = (u32*)(ws + O_BAR);
  u16* wp  = (u16*)(ws + O_WP);
  u64* xwp = (u64*)(ws + O_XWP);
  u16* sh  = (u16*)(ws + O_SH);
  u16* hh  = (u16*)(ws + O_HH);

  const int LDS_BYTES = 147456 + 3072;
  hipFuncSetAttribute((const void*)recur_kernel,
                      hipFuncAttributeMaxDynamicSharedMemorySize, LDS_BYTES);

  hipMemsetAsync(bar, 0, 8192, stream);  // zero barrier flags every call
  pack_kernel<<<dim3(2560), dim3(256), 0, stream>>>(w0, wsrc, wp);
  xw_kernel<<<dim3(8192), dim3(256), 0, stream>>>(x_in, wp, xwp);
  init_hh<<<dim3(128), dim3(256), 0, stream>>>(h_in, hh);
  recur_kernel<<<dim3(128), dim3(256), LDS_BYTES, stream>>>(xwp, h_in, wp, sh, hh, bar, out);
}